// Round 8
// baseline (37.060 us; speedup 1.0000x reference)
//
#include <hip/hip_runtime.h>

// N_TOTAL=10100, D=128, B=2048. F dense-stored, ~33 nnz/row.
// One row per block, TPB=256 (4 waves). Wave-autonomous:
//   wave w owns quarter [w*2528, ...) of the row:
//     P1: float4 scan, ballot-compaction (no atomics). UNIFORM trip count:
//         every lane runs all rounds with a predicated load, so ballots and
//         the running count cb are wave-collective (R7 bug fix).
//     P2: immediately (no barrier) sparse-aggregate own entries; lane l owns
//         d=(2l,2l+1) as float2; x4 unrolled independent gathers.
//   then 2 barriers: cross-wave reduce -> fused linear epilogue (coalesced W
//   float4 + 32-lane shuffle reduce).

#define NTOT 10100
#define NV4  2525     // NTOT/4 exact
#define QV4  632      // float4s per wave-quarter (waves 0-2: 632, wave 3: 629)
#define DIM  128
#define WCAP 80       // per-wave capacity; quarter nnz ~ Poisson(8); dense fallback if over
#define TPB  256

__global__ __launch_bounds__(TPB) void friendship_kernel(
    const int*   __restrict__ uids,
    const float* __restrict__ F,
    const float* __restrict__ E,
    const float* __restrict__ W,
    const float* __restrict__ bias,
    float*       __restrict__ out)
{
    __shared__ int   s_idx[4][WCAP];
    __shared__ float s_w[4][WCAP];
    __shared__ float s_part[4][DIM];
    __shared__ float s_agg[DIM];
    __shared__ float s_out[DIM];

    const int row  = blockIdx.x;
    const int tid  = threadIdx.x;
    const int w    = tid >> 6;          // wave 0..3
    const int lane = tid & 63;
    const int uid  = uids[row];
    const float* Frow = F + (size_t)uid * NTOT;
    const float4* Frow4 = (const float4*)Frow;   // uid*40400 % 16 == 0

    const int jbeg = w * QV4;
    const int jend = (w == 3) ? NV4 : (jbeg + QV4);
    const unsigned long long below = (1ULL << lane) - 1ULL;
    const int nrounds = (jend - jbeg + 63) >> 6;   // == 10 for every wave

    // ---- P1: ballot-compaction, uniform rounds (no atomics, no divergence) ----
    int cb = 0;   // wave-uniform running count (every lane does every round)
    for (int t = 0; t < nrounds; ++t) {
        const int j = jbeg + t * 64 + lane;
        float4 v = make_float4(0.f, 0.f, 0.f, 0.f);
        if (j < jend) v = Frow4[j];               // predicated; OOB lanes contribute zeros
        bool b0 = v.x != 0.0f, b1 = v.y != 0.0f, b2 = v.z != 0.0f, b3 = v.w != 0.0f;
        unsigned long long m0 = __ballot(b0), m1 = __ballot(b1);
        unsigned long long m2 = __ballot(b2), m3 = __ballot(b3);
        if (m0 | m1 | m2 | m3) {                  // wave-uniform fast path
            int t0 = __popcll(m0), t1 = __popcll(m1), t2 = __popcll(m2);
            int n = j * 4;
            int p0 = cb + __popcll(m0 & below);
            int p1 = cb + t0 + __popcll(m1 & below);
            int p2 = cb + t0 + t1 + __popcll(m2 & below);
            int p3 = cb + t0 + t1 + t2 + __popcll(m3 & below);
            // exact guards: entry at position p is stored iff p < WCAP; the
            // sparse path below is taken only when cb_final <= WCAP, in which
            // case every counted position was < WCAP and thus stored.
            if (b0 && p0 < WCAP) { s_idx[w][p0] = n;     s_w[w][p0] = v.x; }
            if (b1 && p1 < WCAP) { s_idx[w][p1] = n + 1; s_w[w][p1] = v.y; }
            if (b2 && p2 < WCAP) { s_idx[w][p2] = n + 2; s_w[w][p2] = v.z; }
            if (b3 && p3 < WCAP) { s_idx[w][p3] = n + 3; s_w[w][p3] = v.w; }
            cb += t0 + t1 + t2 + __popcll(m3);
        }
    }
    // drain this wave's ds_writes; same-wave lockstep => data visible to all lanes
    asm volatile("s_waitcnt lgkmcnt(0)" ::: "memory");
    __builtin_amdgcn_sched_barrier(0);

    // ---- P2: this wave's partial aggregate, lane owns d=(2l,2l+1) ----
    float2 acc = make_float2(0.0f, 0.0f);
    const float* Ed = E + 2 * lane;
    if (cb <= WCAP) {
        int k = 0;
        for (; k + 4 <= cb; k += 4) {
            int   n0 = s_idx[w][k],     n1 = s_idx[w][k + 1];
            int   n2 = s_idx[w][k + 2], n3 = s_idx[w][k + 3];
            float w0 = s_w[w][k],       w1 = s_w[w][k + 1];
            float w2 = s_w[w][k + 2],   w3 = s_w[w][k + 3];
            float2 e0 = *(const float2*)(Ed + (size_t)n0 * DIM);
            float2 e1 = *(const float2*)(Ed + (size_t)n1 * DIM);
            float2 e2 = *(const float2*)(Ed + (size_t)n2 * DIM);
            float2 e3 = *(const float2*)(Ed + (size_t)n3 * DIM);
            acc.x += w0 * e0.x; acc.y += w0 * e0.y;
            acc.x += w1 * e1.x; acc.y += w1 * e1.y;
            acc.x += w2 * e2.x; acc.y += w2 * e2.y;
            acc.x += w3 * e3.x; acc.y += w3 * e3.y;
        }
        for (; k < cb; ++k) {
            int   n = s_idx[w][k];
            float ww = s_w[w][k];
            float2 ev = *(const float2*)(Ed + (size_t)n * DIM);
            acc.x += ww * ev.x; acc.y += ww * ev.y;
        }
    } else {
        // dense fallback over this wave's quarter (never taken; correctness net)
        int nbeg = jbeg * 4, nend = (w == 3) ? NTOT : (jend * 4);
        for (int n = nbeg; n < nend; ++n) {
            float fw = Frow[n];
            if (fw != 0.0f) {
                float2 ev = *(const float2*)(Ed + (size_t)n * DIM);
                acc.x += fw * ev.x; acc.y += fw * ev.y;
            }
        }
    }
    *(float2*)&s_part[w][2 * lane] = acc;
    __syncthreads();

    // ---- cross-wave reduce ----
    if (tid < DIM)
        s_agg[tid] = s_part[0][tid] + s_part[1][tid] + s_part[2][tid] + s_part[3][tid];
    __syncthreads();

    // ---- P3: out[j] = bias[j] + sum_d agg[d]*W[j][d]; coalesced W ----
    const float4* W4 = (const float4*)W;
    #pragma unroll
    for (int q = 0; q < 16; ++q) {
        int i4 = tid + TPB * q;          // flat float4 index 0..4095
        float4 wv = W4[i4];              // fully coalesced, L2-hot
        int j  = i4 >> 5;
        int dd = (i4 & 31) * 4;
        float4 ag = *(const float4*)&s_agg[dd];
        float p = wv.x * ag.x + wv.y * ag.y + wv.z * ag.z + wv.w * ag.w;
        p += __shfl_xor(p, 16);
        p += __shfl_xor(p, 8);
        p += __shfl_xor(p, 4);
        p += __shfl_xor(p, 2);
        p += __shfl_xor(p, 1);
        if ((tid & 31) == 0) s_out[j] = p;
    }
    __syncthreads();
    if (tid < DIM)
        out[(size_t)row * DIM + tid] = bias[tid] + s_out[tid];
}

extern "C" void kernel_launch(void* const* d_in, const int* in_sizes, int n_in,
                              void* d_out, int out_size, void* d_ws, size_t ws_size,
                              hipStream_t stream) {
    const int*   uids = (const int*)  d_in[0];
    const float* F    = (const float*)d_in[1];
    const float* E    = (const float*)d_in[2];
    const float* W    = (const float*)d_in[3];
    const float* bias = (const float*)d_in[4];
    float*       out  = (float*)d_out;

    const int B = in_sizes[0];  // 2048
    friendship_kernel<<<B, TPB, 0, stream>>>(uids, F, E, W, bias, out);
}

// Round 9
// 32.771 us; speedup vs baseline: 1.1309x; 1.1309x over previous
//
#include <hip/hip_runtime.h>

// N_TOTAL=10100, D=128, B=2048. F dense-stored, ~33 nnz/row.
// One row per block, TPB=256 (4 waves), wave-autonomous quarters.
//   P1 (lean stream): per 64-chunk round: 1 float4 load, 4 cmp, 1 OR, 1 ballot,
//      chunk-granular compaction (index + raw float4 to LDS; ONE divergent
//      store region per round, ~3 lanes active). No atomics, no per-element
//      prefix chains in the hot loop.
//   P2 (expand, no barrier): wave walks its compacted chunks from LDS
//      (broadcast reads, wave-uniform branches on the 4 components); lane l
//      owns d=(2l,2l+1); coalesced float2 E-row gathers.
//   Then: cross-wave reduce -> fused linear epilogue (coalesced W float4 +
//   32-lane shuffle reduce) — structure verified in R8.

#define NTOT 10100
#define NV4  2525     // NTOT/4 exact (4*NV4 == NTOT)
#define DIM  128
#define TPB  256
#define RPW  10       // rounds per wave (40 rounds of 64 chunks cover 2560 >= NV4)
#define WCAP 64       // compacted-chunk capacity per wave; quarter ~Poisson(8.25)

__global__ __launch_bounds__(TPB) void friendship_kernel(
    const int*   __restrict__ uids,
    const float* __restrict__ F,
    const float* __restrict__ E,
    const float* __restrict__ W,
    const float* __restrict__ bias,
    float*       __restrict__ out)
{
    __shared__ int    s_n[4][WCAP];     // chunk index (float4 units)
    __shared__ float4 s_v[4][WCAP];     // raw chunk values
    __shared__ float  s_part[4][DIM];
    __shared__ float  s_agg[DIM];
    __shared__ float  s_out[DIM];

    const int row  = blockIdx.x;
    const int tid  = threadIdx.x;
    const int w    = tid >> 6;          // wave 0..3
    const int lane = tid & 63;
    const int uid  = uids[row];
    const float* Frow = F + (size_t)uid * NTOT;
    const float4* Frow4 = (const float4*)Frow;   // uid*40400 % 16 == 0
    const unsigned long long below = (1ULL << lane) - 1ULL;

    // ---- P1: lean stream + chunk-granular ballot compaction ----
    int  cb  = 0;        // wave-uniform compacted count
    bool ovf = false;    // wave-uniform overflow flag
    #pragma unroll
    for (int t = 0; t < RPW; ++t) {
        const int j = 640 * w + 64 * t + lane;
        float4 v = make_float4(0.f, 0.f, 0.f, 0.f);
        if (j < NV4) v = Frow4[j];      // full rounds: all-lane mask, ~free
        const bool nz = (v.x != 0.0f) | (v.y != 0.0f) | (v.z != 0.0f) | (v.w != 0.0f);
        const unsigned long long m = __ballot(nz);
        if (m) {                        // wave-uniform
            const int cnt = __popcll(m);
            if (cb + cnt <= WCAP) {     // wave-uniform
                const int p = cb + __popcll(m & below);
                if (nz) { s_n[w][p] = j; s_v[w][p] = v; }   // one store region
                cb += cnt;
            } else {
                ovf = true;
            }
        }
    }
    // drain this wave's ds_writes; wave lockstep => visible to all its lanes
    asm volatile("s_waitcnt lgkmcnt(0)" ::: "memory");
    __builtin_amdgcn_sched_barrier(0);

    // ---- P2: expand compacted chunks; lane owns d=(2l,2l+1) ----
    float2 acc = make_float2(0.0f, 0.0f);
    const float* Ed = E + 2 * lane;
    if (!ovf) {
        for (int k = 0; k < cb; ++k) {
            const int    j4 = s_n[w][k];    // LDS broadcast (wave-uniform)
            const float4 v  = s_v[w][k];    // LDS broadcast
            const int n = j4 * 4;
            if (v.x != 0.0f) { float2 e = *(const float2*)(Ed + (size_t)(n    ) * DIM); acc.x += v.x * e.x; acc.y += v.x * e.y; }
            if (v.y != 0.0f) { float2 e = *(const float2*)(Ed + (size_t)(n + 1) * DIM); acc.x += v.y * e.x; acc.y += v.y * e.y; }
            if (v.z != 0.0f) { float2 e = *(const float2*)(Ed + (size_t)(n + 2) * DIM); acc.x += v.z * e.x; acc.y += v.z * e.y; }
            if (v.w != 0.0f) { float2 e = *(const float2*)(Ed + (size_t)(n + 3) * DIM); acc.x += v.w * e.x; acc.y += v.w * e.y; }
        }
    } else {
        // dense fallback over this wave's quarter (never taken in practice)
        const int nbeg = 2560 * w;
        const int nend = (2560 * (w + 1) < NTOT) ? 2560 * (w + 1) : NTOT;
        for (int n = nbeg; n < nend; ++n) {
            float fw = Frow[n];
            if (fw != 0.0f) {
                float2 e = *(const float2*)(Ed + (size_t)n * DIM);
                acc.x += fw * e.x; acc.y += fw * e.y;
            }
        }
    }
    *(float2*)&s_part[w][2 * lane] = acc;
    __syncthreads();

    // ---- cross-wave reduce ----
    if (tid < DIM)
        s_agg[tid] = s_part[0][tid] + s_part[1][tid] + s_part[2][tid] + s_part[3][tid];
    __syncthreads();

    // ---- P3: out[j] = bias[j] + sum_d agg[d]*W[j][d]; coalesced W ----
    const float4* W4 = (const float4*)W;
    #pragma unroll
    for (int q = 0; q < 16; ++q) {
        int i4 = tid + TPB * q;          // flat float4 index 0..4095
        float4 wv = W4[i4];              // fully coalesced, L2-hot
        int j  = i4 >> 5;
        int dd = (i4 & 31) * 4;
        float4 ag = *(const float4*)&s_agg[dd];
        float p = wv.x * ag.x + wv.y * ag.y + wv.z * ag.z + wv.w * ag.w;
        p += __shfl_xor(p, 16);
        p += __shfl_xor(p, 8);
        p += __shfl_xor(p, 4);
        p += __shfl_xor(p, 2);
        p += __shfl_xor(p, 1);
        if ((tid & 31) == 0) s_out[j] = p;
    }
    __syncthreads();
    if (tid < DIM)
        out[(size_t)row * DIM + tid] = bias[tid] + s_out[tid];
}

extern "C" void kernel_launch(void* const* d_in, const int* in_sizes, int n_in,
                              void* d_out, int out_size, void* d_ws, size_t ws_size,
                              hipStream_t stream) {
    const int*   uids = (const int*)  d_in[0];
    const float* F    = (const float*)d_in[1];
    const float* E    = (const float*)d_in[2];
    const float* W    = (const float*)d_in[3];
    const float* bias = (const float*)d_in[4];
    float*       out  = (float*)d_out;

    const int B = in_sizes[0];  // 2048
    friendship_kernel<<<B, TPB, 0, stream>>>(uids, F, E, W, bias, out);
}